// Round 1
// baseline (37356.943 us; speedup 1.0000x reference)
//
#include <hip/hip_runtime.h>
#include <math.h>

#define NTH 256
#define BT  32

#define MEAN_OFF 33554432u   // 64*8192*64
#define LV_OFF   34603008u   // MEAN_OFF + 8192*128

// ---- staging helpers: one 8192-float (32KB) chunk, 8 float4 per thread ----
__device__ __forceinline__ void stage_load(const float* __restrict__ g, float4 (&r)[8], int tid) {
#pragma unroll
  for (int u = 0; u < 8; ++u)
    r[u] = *(const float4*)(g + u * 1024 + tid * 4);
}
__device__ __forceinline__ void stage_store(float* __restrict__ l, const float4 (&r)[8], int tid) {
#pragma unroll
  for (int u = 0; u < 8; ++u)
    *(float4*)(l + u * 1024 + tid * 4) = r[u];
}

// ---- G1-type chunk: A[32 x K] @ W[32 x 256] (rows=32 of k), R=8 x C=4(split) ----
// thread cols = {c, c+1, c+128, c+129}; A rows r..r+7, row stride SA (compile-time)
template<int SA>
__device__ __forceinline__ void g1_chunk(const float* __restrict__ A,
                                         const float* __restrict__ W,
                                         int c, float (&acc)[8][4]) {
#pragma unroll 4
  for (int j4 = 0; j4 < 8; ++j4) {
    const int kk = j4 * 4;
    float4 a[8];
#pragma unroll
    for (int i = 0; i < 8; ++i)
      a[i] = *(const float4*)(A + i * SA + kk);
    float2 wl[4], wh[4];
#pragma unroll
    for (int j = 0; j < 4; ++j) {
      wl[j] = *(const float2*)(W + (kk + j) * 256 + c);
      wh[j] = *(const float2*)(W + (kk + j) * 256 + c + 128);
    }
#pragma unroll
    for (int i = 0; i < 8; ++i) {
      const float af[4] = {a[i].x, a[i].y, a[i].z, a[i].w};
#pragma unroll
      for (int j = 0; j < 4; ++j) {
        acc[i][0] = fmaf(af[j], wl[j].x, acc[i][0]);
        acc[i][1] = fmaf(af[j], wl[j].y, acc[i][1]);
        acc[i][2] = fmaf(af[j], wh[j].x, acc[i][2]);
        acc[i][3] = fmaf(af[j], wh[j].y, acc[i][3]);
      }
    }
  }
}

// ---- G2 chunk: TMP[32 x 256] @ W2[64 x 128] (64 k-rows), R=4 x C=4 ----
__device__ __forceinline__ void g2_chunk(const float* __restrict__ A,
                                         const float* __restrict__ W,
                                         int c, float (&acc)[4][4]) {
#pragma unroll 4
  for (int j4 = 0; j4 < 16; ++j4) {
    const int kk = j4 * 4;
    float4 a[4];
#pragma unroll
    for (int i = 0; i < 4; ++i)
      a[i] = *(const float4*)(A + i * 256 + kk);
    float4 w[4];
#pragma unroll
    for (int j = 0; j < 4; ++j)
      w[j] = *(const float4*)(W + (kk + j) * 128 + c);
#pragma unroll
    for (int i = 0; i < 4; ++i) {
      const float af[4] = {a[i].x, a[i].y, a[i].z, a[i].w};
#pragma unroll
      for (int j = 0; j < 4; ++j) {
        acc[i][0] = fmaf(af[j], w[j].x, acc[i][0]);
        acc[i][1] = fmaf(af[j], w[j].y, acc[i][1]);
        acc[i][2] = fmaf(af[j], w[j].z, acc[i][2]);
        acc[i][3] = fmaf(af[j], w[j].w, acc[i][3]);
      }
    }
  }
}

// ---- decoder G2 chunk: TMP[32 x 256] @ Wd2[128 x 64] (128 k-rows), R=4 x C=2 ----
__device__ __forceinline__ void gd2_chunk(const float* __restrict__ A,
                                          const float* __restrict__ W,
                                          int c, float (&acc)[4][2]) {
#pragma unroll 4
  for (int j4 = 0; j4 < 32; ++j4) {
    const int kk = j4 * 4;
    float4 a[4];
#pragma unroll
    for (int i = 0; i < 4; ++i)
      a[i] = *(const float4*)(A + i * 256 + kk);
    float2 w[4];
#pragma unroll
    for (int j = 0; j < 4; ++j)
      w[j] = *(const float2*)(W + (kk + j) * 64 + c);
#pragma unroll
    for (int i = 0; i < 4; ++i) {
      const float af[4] = {a[i].x, a[i].y, a[i].z, a[i].w};
#pragma unroll
      for (int j = 0; j < 4; ++j) {
        acc[i][0] = fmaf(af[j], w[j].x, acc[i][0]);
        acc[i][1] = fmaf(af[j], w[j].y, acc[i][1]);
      }
    }
  }
}

extern "C" __global__ void __launch_bounds__(NTH, 1)
latent_ode_fused(const float* __restrict__ obs,
                 const float* __restrict__ ptimes,
                 const float* __restrict__ eps,
                 const float* __restrict__ Wi2h, const float* __restrict__ bi2h,
                 const float* __restrict__ Wh2o, const float* __restrict__ bh2o,
                 const float* __restrict__ Wode1, const float* __restrict__ bode1,
                 const float* __restrict__ Wode2, const float* __restrict__ bode2,
                 const float* __restrict__ Wdec1, const float* __restrict__ bdec1,
                 const float* __restrict__ Wdec2, const float* __restrict__ bdec2,
                 float* __restrict__ out)
{
  // 112 KB LDS carve (phase-aliased):
  //  [0,8192)      : encoder H[32][256]   | ODE: ZC[32][128] @0 (4096) , TMP[32][256] @4096
  //  [8192,12288)  : encoder XS dbuf 2x[32][64] (aliases TMP upper half; phases disjoint)
  //  [12288,28672) : weight chunk double buffer, 2 x 8192 floats
  __shared__ float smem[28672];
  float* const H     = smem;
  float* const ZC    = smem;
  float* const TMP   = smem + 4096;
  float* const XS    = smem + 8192;
  float* const WBUF0 = smem + 12288;
  float* const WBUF1 = smem + 20480;

  const int tid = threadIdx.x;
  const int b0  = blockIdx.x * BT;

  // G1-type ownership (R8 x C4 split cols)
  const int c1 = (tid & 63) * 2;
  const int r1 = (tid >> 6) * 8;
  // G2 ownership (R4 x C4)
  const int c2 = (tid & 31) * 4;
  const int r2 = (tid >> 5) * 4;
  // decoder-G2 ownership (R4 x C2)
  const int cd = (tid & 31) * 2;
  const int rd = (tid >> 5) * 4;

  // biases in registers
  const float be[4]  = {bi2h[c1],  bi2h[c1+1],  bi2h[c1+128],  bi2h[c1+129]};
  const float bm[4]  = {bh2o[c1],  bh2o[c1+1],  bh2o[c1+128],  bh2o[c1+129]};
  const float bo1[4] = {bode1[c1], bode1[c1+1], bode1[c1+128], bode1[c1+129]};
  const float4 bo2v  = *(const float4*)(bode2 + c2);
  const float bd1[4] = {bdec1[c1], bdec1[c1+1], bdec1[c1+128], bdec1[c1+129]};
  const float2 bd2v  = *(const float2*)(bdec2 + cd);

  // zero H (initial hidden state)
  for (int u = tid; u < 2048; u += NTH)
    *(float4*)(smem + u * 4) = make_float4(0.f, 0.f, 0.f, 0.f);

  // prologue: stage Xs(s=127) into XS buf1, Wi2h chunk0 into WBUF0
  {
#pragma unroll
    for (int u = 0; u < 2; ++u) {
      const int idx = u * NTH + tid;
      const int rr = idx >> 4, kp = (idx & 15) * 4;
      float4 x = *(const float4*)(obs + ((size_t)(b0 + rr) * 128 + 127) * 64 + kp);
      *(float4*)(XS + 2048 + idx * 4) = x;
    }
    float4 wr[8];
    stage_load(Wi2h, wr, tid);
    stage_store(WBUF0, wr, tid);
  }

  float acc[8][4];
#pragma unroll
  for (int i = 0; i < 8; ++i) { acc[i][0]=be[0]; acc[i][1]=be[1]; acc[i][2]=be[2]; acc[i][3]=be[3]; }

  // ================= encoder: 128 reversed RNN steps =================
#pragma unroll 1
  for (int it = 0; it < 128; ++it) {
    const int s = 127 - it;
    const float* xs_cur = XS + (s & 1) * 2048;
    float4 xr[2];
#pragma unroll 1
    for (int c = 0; c < 10; ++c) {
      __syncthreads();
      if (c == 0) {
        if (it > 0) {
#pragma unroll
          for (int i = 0; i < 8; ++i) {
            *(float2*)(H + (r1+i)*256 + c1)       = make_float2(tanhf(acc[i][0]), tanhf(acc[i][1]));
            *(float2*)(H + (r1+i)*256 + c1 + 128) = make_float2(tanhf(acc[i][2]), tanhf(acc[i][3]));
          }
#pragma unroll
          for (int i = 0; i < 8; ++i) { acc[i][0]=be[0]; acc[i][1]=be[1]; acc[i][2]=be[2]; acc[i][3]=be[3]; }
        }
        if (s > 0) {
#pragma unroll
          for (int u = 0; u < 2; ++u) {
            const int idx = u * NTH + tid;
            const int rr = idx >> 4, kp = (idx & 15) * 4;
            xr[u] = *(const float4*)(obs + ((size_t)(b0 + rr) * 128 + (s - 1)) * 64 + kp);
          }
        }
      }
      float4 wr[8];
      const float* nw = (c < 9) ? (Wi2h + (size_t)(c + 1) * 8192)
                                : ((it < 127) ? Wi2h : Wh2o);
      stage_load(nw, wr, tid);
      const float* wc = (c & 1) ? WBUF1 : WBUF0;
      if (c < 2) g1_chunk<64>(xs_cur + r1 * 64 + 32 * c, wc, c1, acc);
      else       g1_chunk<256>(H + r1 * 256 + 32 * (c - 2), wc, c1, acc);
      stage_store((c & 1) ? WBUF0 : WBUF1, wr, tid);
      if (c == 0 && s > 0) {
#pragma unroll
        for (int u = 0; u < 2; ++u) {
          const int idx = u * NTH + tid;
          *(float4*)(XS + ((s - 1) & 1) * 2048 + idx * 4) = xr[u];
        }
      }
    }
  }

  // ================= h_final -> (z0_mean, z0_logvar) -> z0 =================
  __syncthreads();
#pragma unroll
  for (int i = 0; i < 8; ++i) {
    *(float2*)(H + (r1+i)*256 + c1)       = make_float2(tanhf(acc[i][0]), tanhf(acc[i][1]));
    *(float2*)(H + (r1+i)*256 + c1 + 128) = make_float2(tanhf(acc[i][2]), tanhf(acc[i][3]));
  }
#pragma unroll
  for (int i = 0; i < 8; ++i) { acc[i][0]=bm[0]; acc[i][1]=bm[1]; acc[i][2]=bm[2]; acc[i][3]=bm[3]; }
#pragma unroll 1
  for (int c = 0; c < 8; ++c) {
    __syncthreads();
    float4 wr[8];
    const float* nw = (c < 7) ? (Wh2o + (size_t)(c + 1) * 8192) : Wdec1;
    stage_load(nw, wr, tid);
    g1_chunk<256>(H + r1 * 256 + 32 * c, (c & 1) ? WBUF1 : WBUF0, c1, acc);
    stage_store((c & 1) ? WBUF0 : WBUF1, wr, tid);
  }
  __syncthreads();   // all H reads done; safe to overwrite [0,4096) with ZC
#pragma unroll
  for (int i = 0; i < 8; ++i) {
    const float2 e = *(const float2*)(eps + (size_t)(b0 + r1 + i) * 128 + c1);
    const float m0 = acc[i][0], m1 = acc[i][1], l0 = acc[i][2], l1 = acc[i][3];
    *(float2*)(out + MEAN_OFF + (size_t)(b0 + r1 + i) * 128 + c1) = make_float2(m0, m1);
    *(float2*)(out + LV_OFF   + (size_t)(b0 + r1 + i) * 128 + c1) = make_float2(l0, l1);
    const float z0a = m0 + e.x * expf(0.5f * l0);
    const float z0b = m1 + e.y * expf(0.5f * l1);
    *(float2*)(ZC + (r1 + i) * 128 + c1) = make_float2(z0a, z0b);
  }
  __syncthreads();

  // z registers in G2-ownership
  float z[4][4];
#pragma unroll
  for (int i = 0; i < 4; ++i) {
    float4 t = *(const float4*)(ZC + (r2 + i) * 128 + c2);
    z[i][0] = t.x; z[i][1] = t.y; z[i][2] = t.z; z[i][3] = t.w;
  }

  // ---- decode: hdec = relu(ZC @ Wdec1 + b), P = hdec @ Wdec2 + b -> out[t] ----
  auto decode = [&](int t, const float* nextW) {
    float a1[8][4];
#pragma unroll
    for (int i = 0; i < 8; ++i) { a1[i][0]=bd1[0]; a1[i][1]=bd1[1]; a1[i][2]=bd1[2]; a1[i][3]=bd1[3]; }
#pragma unroll 1
    for (int c = 0; c < 4; ++c) {
      __syncthreads();
      float4 wr[8];
      const float* nw = (c < 3) ? (Wdec1 + (size_t)(c + 1) * 8192) : Wdec2;
      stage_load(nw, wr, tid);
      g1_chunk<128>(ZC + r1 * 128 + 32 * c, (c & 1) ? WBUF1 : WBUF0, c1, a1);
      stage_store((c & 1) ? WBUF0 : WBUF1, wr, tid);
    }
#pragma unroll
    for (int i = 0; i < 8; ++i) {
      *(float2*)(TMP + (r1+i)*256 + c1)       = make_float2(fmaxf(a1[i][0],0.f), fmaxf(a1[i][1],0.f));
      *(float2*)(TMP + (r1+i)*256 + c1 + 128) = make_float2(fmaxf(a1[i][2],0.f), fmaxf(a1[i][3],0.f));
    }
    float a2[4][2];
#pragma unroll
    for (int i = 0; i < 4; ++i) { a2[i][0] = bd2v.x; a2[i][1] = bd2v.y; }
#pragma unroll 1
    for (int c = 0; c < 2; ++c) {
      __syncthreads();
      float4 wr[8];
      const float* nw = (c < 1) ? (Wdec2 + 8192) : nextW;
      stage_load(nw, wr, tid);
      gd2_chunk(TMP + rd * 256 + 128 * c, (c & 1) ? WBUF1 : WBUF0, cd, a2);
      stage_store((c & 1) ? WBUF0 : WBUF1, wr, tid);
    }
#pragma unroll
    for (int i = 0; i < 4; ++i)
      *(float2*)(out + (size_t)t * 524288 + (size_t)(b0 + rd + i) * 64 + cd)
          = make_float2(a2[i][0], a2[i][1]);
  };

  // ---- f(zc) = tanh(zc @ Wode1 + b1) @ Wode2 + b2, result in G2-ownership ----
  auto feval = [&](const float* nextW, float (&f)[4][4]) {
    float a1[8][4];
#pragma unroll
    for (int i = 0; i < 8; ++i) { a1[i][0]=bo1[0]; a1[i][1]=bo1[1]; a1[i][2]=bo1[2]; a1[i][3]=bo1[3]; }
#pragma unroll 1
    for (int c = 0; c < 4; ++c) {
      __syncthreads();
      float4 wr[8];
      const float* nw = (c < 3) ? (Wode1 + (size_t)(c + 1) * 8192) : Wode2;
      stage_load(nw, wr, tid);
      g1_chunk<128>(ZC + r1 * 128 + 32 * c, (c & 1) ? WBUF1 : WBUF0, c1, a1);
      stage_store((c & 1) ? WBUF0 : WBUF1, wr, tid);
    }
#pragma unroll
    for (int i = 0; i < 8; ++i) {
      *(float2*)(TMP + (r1+i)*256 + c1)       = make_float2(tanhf(a1[i][0]), tanhf(a1[i][1]));
      *(float2*)(TMP + (r1+i)*256 + c1 + 128) = make_float2(tanhf(a1[i][2]), tanhf(a1[i][3]));
    }
    float a2[4][4];
#pragma unroll
    for (int i = 0; i < 4; ++i) { a2[i][0]=bo2v.x; a2[i][1]=bo2v.y; a2[i][2]=bo2v.z; a2[i][3]=bo2v.w; }
#pragma unroll 1
    for (int c = 0; c < 4; ++c) {
      __syncthreads();
      float4 wr[8];
      const float* nw = (c < 3) ? (Wode2 + (size_t)(c + 1) * 8192) : nextW;
      stage_load(nw, wr, tid);
      g2_chunk(TMP + r2 * 256 + 64 * c, (c & 1) ? WBUF1 : WBUF0, c2, a2);
      stage_store((c & 1) ? WBUF0 : WBUF1, wr, tid);
    }
#pragma unroll
    for (int i = 0; i < 4; ++i) {
      f[i][0]=a2[i][0]; f[i][1]=a2[i][1]; f[i][2]=a2[i][2]; f[i][3]=a2[i][3];
    }
  };

  decode(0, Wode1);

  // ================= 63 intervals x 4 RK4 substeps =================
  float kacc[4][4];
#pragma unroll 1
  for (int t = 0; t < 63; ++t) {
    const float dt = (ptimes[t + 1] - ptimes[t]) * 0.25f;
#pragma unroll 1
    for (int ss = 0; ss < 4; ++ss) {
      float f[4][4];
      // k1
      feval(Wode1, f);
      {
        const float h = 0.5f * dt;
#pragma unroll
        for (int i = 0; i < 4; ++i) {
          float4 v;
          kacc[i][0] = f[i][0]; v.x = fmaf(h, f[i][0], z[i][0]);
          kacc[i][1] = f[i][1]; v.y = fmaf(h, f[i][1], z[i][1]);
          kacc[i][2] = f[i][2]; v.z = fmaf(h, f[i][2], z[i][2]);
          kacc[i][3] = f[i][3]; v.w = fmaf(h, f[i][3], z[i][3]);
          *(float4*)(ZC + (r2 + i) * 128 + c2) = v;
        }
      }
      // k2
      feval(Wode1, f);
      {
        const float h = 0.5f * dt;
#pragma unroll
        for (int i = 0; i < 4; ++i) {
          float4 v;
          kacc[i][0] = fmaf(2.f, f[i][0], kacc[i][0]); v.x = fmaf(h, f[i][0], z[i][0]);
          kacc[i][1] = fmaf(2.f, f[i][1], kacc[i][1]); v.y = fmaf(h, f[i][1], z[i][1]);
          kacc[i][2] = fmaf(2.f, f[i][2], kacc[i][2]); v.z = fmaf(h, f[i][2], z[i][2]);
          kacc[i][3] = fmaf(2.f, f[i][3], kacc[i][3]); v.w = fmaf(h, f[i][3], z[i][3]);
          *(float4*)(ZC + (r2 + i) * 128 + c2) = v;
        }
      }
      // k3
      feval(Wode1, f);
      {
#pragma unroll
        for (int i = 0; i < 4; ++i) {
          float4 v;
          kacc[i][0] = fmaf(2.f, f[i][0], kacc[i][0]); v.x = fmaf(dt, f[i][0], z[i][0]);
          kacc[i][1] = fmaf(2.f, f[i][1], kacc[i][1]); v.y = fmaf(dt, f[i][1], z[i][1]);
          kacc[i][2] = fmaf(2.f, f[i][2], kacc[i][2]); v.z = fmaf(dt, f[i][2], z[i][2]);
          kacc[i][3] = fmaf(2.f, f[i][3], kacc[i][3]); v.w = fmaf(dt, f[i][3], z[i][3]);
          *(float4*)(ZC + (r2 + i) * 128 + c2) = v;
        }
      }
      // k4 + state update
      feval((ss < 3) ? Wode1 : Wdec1, f);
      {
        const float h6 = dt * (1.0f / 6.0f);
#pragma unroll
        for (int i = 0; i < 4; ++i) {
          float4 v;
          z[i][0] = fmaf(h6, kacc[i][0] + f[i][0], z[i][0]); v.x = z[i][0];
          z[i][1] = fmaf(h6, kacc[i][1] + f[i][1], z[i][1]); v.y = z[i][1];
          z[i][2] = fmaf(h6, kacc[i][2] + f[i][2], z[i][2]); v.z = z[i][2];
          z[i][3] = fmaf(h6, kacc[i][3] + f[i][3], z[i][3]); v.w = z[i][3];
          *(float4*)(ZC + (r2 + i) * 128 + c2) = v;
        }
      }
    }
    decode(t + 1, Wode1);
  }
}

extern "C" void kernel_launch(void* const* d_in, const int* in_sizes, int n_in,
                              void* d_out, int out_size, void* d_ws, size_t ws_size,
                              hipStream_t stream) {
  const float* obs    = (const float*)d_in[0];
  // d_in[1] = observed_times (unused by the reference)
  const float* ptimes = (const float*)d_in[2];
  const float* eps    = (const float*)d_in[3];
  const float* Wi2h   = (const float*)d_in[4];
  const float* bi2h   = (const float*)d_in[5];
  const float* Wh2o   = (const float*)d_in[6];
  const float* bh2o   = (const float*)d_in[7];
  const float* Wode1  = (const float*)d_in[8];
  const float* bode1  = (const float*)d_in[9];
  const float* Wode2  = (const float*)d_in[10];
  const float* bode2  = (const float*)d_in[11];
  const float* Wdec1  = (const float*)d_in[12];
  const float* bdec1  = (const float*)d_in[13];
  const float* Wdec2  = (const float*)d_in[14];
  const float* bdec2  = (const float*)d_in[15];

  latent_ode_fused<<<dim3(8192 / BT), dim3(NTH), 0, stream>>>(
      obs, ptimes, eps, Wi2h, bi2h, Wh2o, bh2o,
      Wode1, bode1, Wode2, bode2, Wdec1, bdec1, Wdec2, bdec2,
      (float*)d_out);
}